// Round 13
// baseline (281.086 us; speedup 1.0000x reference)
//
#include <hip/hip_runtime.h>

constexpr int Bn = 8, Cn = 3, Hn = 720, Wn = 1280;
constexpr int HW = Hn * Wn;                    // 921600 px per image
constexpr long long NTOT = (long long)Bn * Cn * HW;

constexpr int BLK  = 256;
constexpr int TH   = 16, TW = 64;              // output tile 16x64 = 1024 px
constexpr int TPX  = TH * TW;
constexpr int TCOL = Wn / TW;                  // 20 tile-cols
constexpr int TPI  = (Hn / TH) * TCOL;         // 900 tiles per image
constexpr int NWG  = 8 * TPI;                  // 7200 blocks; bid&7 = image/XCD
constexpr int PXT  = TPX / BLK;                // 4 px per thread
constexpr int WR   = 24;                       // window rows: Y-4 .. Y+19 (replicated at borders)
constexpr int WC   = 84;                       // window cols: XS-4 .. XS+79 (stride 84: 16B-aligned rows, bank-friendly)
constexpr int F4W  = WC / 4;                   // 21 f4 per window row
constexpr int F4P  = WR * F4W;                 // 504 f4 per plane

typedef float f4 __attribute__((ext_vector_type(4)));

__global__ __launch_bounds__(256, 8) void warp_loss_kernel(
        const float* __restrict__ L, const float* __restrict__ R,
        const float* __restrict__ Flm, const float* __restrict__ Frm,
        const float* __restrict__ G, double* __restrict__ accum) {
    // XCD k (= bid%8) owns image k; inner = tile id, row-major sweep.
    // Active band per XCD ~12 tile-rows; halo re-reads (1.875x window
    // amplification) hit the XCD L2 (halo distance = 1 tile-row).
    const int b    = blockIdx.x & 7;
    const int t    = blockIdx.x >> 3;          // [0, 900)
    const int trow = t / TCOL;
    const int tcol = t - trow * TCOL;
    const int Y    = trow * TH;
    const int XS   = tcol * TW;
    const int tid  = (int)threadIdx.x;

    const float* __restrict__ Lb = L + (size_t)b * Cn * HW;
    const float* __restrict__ Rb = R + (size_t)b * Cn * HW;
    const float* __restrict__ Gb = G + (size_t)b * Cn * HW;
    const float* __restrict__ fl = Flm + (size_t)b * 2 * HW;  // [0,HW)=x, [HW,2HW)=y
    const float* __restrict__ fr = Frm + (size_t)b * 2 * HW;

    __shared__ float win[2][WR][WC];           // 16.1 KB: L_c and R_c windows

    // ---- per-px tap state (channel-invariant), coalesced flow loads ----
    int   aL[PXT], aR[PXT], pgl[PXT];
    float lwx[PXT], lwy[PXT], rwx[PXT], rwy[PXT];
    #pragma unroll
    for (int k = 0; k < PXT; ++k) {
        const int i = k * BLK + tid;           // tile-local px
        const int r = i >> 6, cm = i & 63;
        const int y = Y + r, x = XS + cm;
        const int p = y * Wn + x;
        pgl[k] = p;
        {   // L warp taps
            float fx = fminf(fmaxf(fl[p],      -4.0f), 3.99951171875f);
            float fy = fminf(fmaxf(fl[HW + p], -4.0f), 3.99951171875f);
            const float xc = fminf(fmaxf((float)x + fx, 0.f), (float)(Wn - 1));
            const float yc = fminf(fmaxf((float)y + fy, 0.f), (float)(Hn - 1));
            const float x0f = floorf(xc), y0f = floorf(yc);
            lwx[k] = xc - x0f;  lwy[k] = yc - y0f;
            aL[k] = ((int)y0f - (Y - 4)) * WC + ((int)x0f - (XS - 4));
        }
        {   // R warp taps
            float fx = fminf(fmaxf(fr[p],      -4.0f), 3.99951171875f);
            float fy = fminf(fmaxf(fr[HW + p], -4.0f), 3.99951171875f);
            const float xc = fminf(fmaxf((float)x + fx, 0.f), (float)(Wn - 1));
            const float yc = fminf(fmaxf((float)y + fy, 0.f), (float)(Hn - 1));
            const float x0f = floorf(xc), y0f = floorf(yc);
            rwx[k] = xc - x0f;  rwy[k] = yc - y0f;
            aR[k] = ((int)y0f - (Y - 4)) * WC + ((int)x0f - (XS - 4));
        }
    }

    float local = 0.f;

    for (int c = 0; c < Cn; ++c) {
        __syncthreads();                       // prior channel's reads done
        const float* __restrict__ Lc = Lb + (size_t)c * HW;
        const float* __restrict__ Rc = Rb + (size_t)c * HW;
        // ---- stage both windows: 1008 f4, fully coalesced ----
        #pragma unroll
        for (int k = 0; k < 4; ++k) {
            const int idx = k * BLK + tid;
            if (idx < 2 * F4P) {
                const int pl = idx >= F4P;
                const int f  = idx - pl * F4P;
                const int wr = f / F4W;
                const int c4 = f - wr * F4W;
                const int ys = min(max(Y - 4 + wr, 0), Hn - 1);
                const int xw = XS - 4 + c4 * 4;
                const float* __restrict__ src = (pl ? Rc : Lc) + (size_t)ys * Wn;
                f4 v;
                if (xw >= 0 && xw + 3 < Wn) {
                    v = *reinterpret_cast<const f4*>(src + xw);   // 16B-aligned
                } else {
                    v[0] = src[min(max(xw,     0), Wn - 1)];
                    v[1] = src[min(max(xw + 1, 0), Wn - 1)];
                    v[2] = src[min(max(xw + 2, 0), Wn - 1)];
                    v[3] = src[min(max(xw + 3, 0), Wn - 1)];
                }
                *reinterpret_cast<f4*>(&win[pl][wr][c4 * 4]) = v;
            }
        }
        __syncthreads();

        // ---- sample from LDS (divergent addressing is what LDS is for) ----
        const float* __restrict__ w0 = &win[0][0][0];
        const float* __restrict__ w1 = &win[1][0][0];
        #pragma unroll
        for (int k = 0; k < PXT; ++k) {
            const float g = Gb[(size_t)c * HW + pgl[k]];
            const int a = aL[k];
            float v00 = w0[a],      v01 = w0[a + 1];
            float v10 = w0[a + WC], v11 = w0[a + WC + 1];
            float top = fmaf(lwx[k], v01 - v00, v00);
            float bot = fmaf(lwx[k], v11 - v10, v10);
            const float sL = fmaf(lwy[k], bot - top, top);
            const int a2 = aR[k];
            v00 = w1[a2];      v01 = w1[a2 + 1];
            v10 = w1[a2 + WC]; v11 = w1[a2 + WC + 1];
            top = fmaf(rwx[k], v01 - v00, v00);
            bot = fmaf(rwx[k], v11 - v10, v10);
            const float sR = fmaf(rwy[k], bot - top, top);
            local += fabsf(sL - g) + fabsf(sR - g);
        }
    }

    // wave(64) shuffle reduce -> LDS cross-wave -> one f64 atomic per block
    #pragma unroll
    for (int off = 32; off > 0; off >>= 1)
        local += __shfl_down(local, off, 64);

    __shared__ float wsum[4];
    const int lane = tid & 63;
    const int wid  = tid >> 6;
    if (lane == 0) wsum[wid] = local;
    __syncthreads();
    if (tid == 0) {
        const float s = wsum[0] + wsum[1] + wsum[2] + wsum[3];
        atomicAdd(accum, (double)s);
    }
}

__global__ void finalize_kernel(const double* __restrict__ accum,
                                float* __restrict__ out) {
    out[0] = (float)(accum[0] / (double)NTOT);
}

extern "C" void kernel_launch(void* const* d_in, const int* in_sizes, int n_in,
                              void* d_out, int out_size, void* d_ws, size_t ws_size,
                              hipStream_t stream) {
    const float* L   = (const float*)d_in[0];
    const float* R   = (const float*)d_in[1];
    const float* flm = (const float*)d_in[2];
    const float* frm = (const float*)d_in[3];
    const float* gt  = (const float*)d_in[4];
    double* accum = (double*)d_ws;

    (void)hipMemsetAsync(accum, 0, sizeof(double), stream);
    warp_loss_kernel<<<NWG, BLK, 0, stream>>>(L, R, flm, frm, gt, accum);
    finalize_kernel<<<1, 1, 0, stream>>>(accum, (float*)d_out);
}

// Round 14
// 132.337 us; speedup vs baseline: 2.1240x; 2.1240x over previous
//
#include <hip/hip_runtime.h>

constexpr int Bn = 8, Cn = 3, Hn = 720, Wn = 1280;
constexpr int HW = Hn * Wn;                    // 921600 px per image
constexpr long long NTOT = (long long)Bn * Cn * HW;

constexpr int BLK  = 256;
constexpr int TH   = 16, TW = 64;              // output tile 16x64 = 1024 px
constexpr int TPX  = TH * TW;
constexpr int TCOL = Wn / TW;                  // 20 tile-cols
constexpr int TPI  = (Hn / TH) * TCOL;         // 900 tiles per image
constexpr int NWG  = 8 * TPI;                  // 7200 blocks; bid&7 = image/XCD
constexpr int PXT  = TPX / BLK;                // 4 px per thread
constexpr int WR   = 24;                       // window rows: Y-4 .. Y+19 (border-replicated)
constexpr int WC   = 84;                       // window cols: XS-4 .. XS+79
constexpr int F4W  = WC / 4;                   // 21 f4 per window row
constexpr int F4P  = WR * F4W;                 // 504 f4 per plane

typedef float f4 __attribute__((ext_vector_type(4)));

__global__ __launch_bounds__(256) void warp_loss_kernel(
        const float* __restrict__ L, const float* __restrict__ R,
        const float* __restrict__ Flm, const float* __restrict__ Frm,
        const float* __restrict__ G, double* __restrict__ accum) {
    // XCD k (= bid%8) owns image k; t = tile id, row-major sweep.
    // Halo re-reads (1.97x window amplification) hit the XCD L2.
    const int b    = blockIdx.x & 7;
    const int t    = blockIdx.x >> 3;          // [0, 900)
    const int trow = t / TCOL;
    const int tcol = t - trow * TCOL;
    const int Y    = trow * TH;
    const int XS   = tcol * TW;
    const int tid  = (int)threadIdx.x;

    const float* __restrict__ Lb = L + (size_t)b * Cn * HW;
    const float* __restrict__ Rb = R + (size_t)b * Cn * HW;
    const float* __restrict__ Gb = G + (size_t)b * Cn * HW;
    const float* __restrict__ fl = Flm + (size_t)b * 2 * HW;  // [0,HW)=x, [HW,2HW)=y
    const float* __restrict__ fr = Frm + (size_t)b * 2 * HW;

    __shared__ float win[2][WR][WC];           // 16.1 KB: L_c and R_c windows

    // ---- per-px tap state (channel-invariant), coalesced flow loads.
    //      6 regs/px x 4 px = 24 regs; statically indexed via unroll. ----
    int   aL[PXT], aR[PXT];
    float lwx[PXT], lwy[PXT], rwx[PXT], rwy[PXT];
    #pragma unroll
    for (int k = 0; k < PXT; ++k) {
        const int i = k * BLK + tid;           // tile-local px
        const int r = i >> 6, cm = i & 63;
        const int y = Y + r, x = XS + cm;
        const int p = y * Wn + x;
        {   // L warp taps
            const float fx = fminf(fmaxf(fl[p],      -4.0f), 3.99951171875f);
            const float fy = fminf(fmaxf(fl[HW + p], -4.0f), 3.99951171875f);
            const float xc = fminf(fmaxf((float)x + fx, 0.f), (float)(Wn - 1));
            const float yc = fminf(fmaxf((float)y + fy, 0.f), (float)(Hn - 1));
            const float x0f = floorf(xc), y0f = floorf(yc);
            lwx[k] = xc - x0f;  lwy[k] = yc - y0f;
            aL[k] = ((int)y0f - (Y - 4)) * WC + ((int)x0f - (XS - 4));
        }
        {   // R warp taps
            const float fx = fminf(fmaxf(fr[p],      -4.0f), 3.99951171875f);
            const float fy = fminf(fmaxf(fr[HW + p], -4.0f), 3.99951171875f);
            const float xc = fminf(fmaxf((float)x + fx, 0.f), (float)(Wn - 1));
            const float yc = fminf(fmaxf((float)y + fy, 0.f), (float)(Hn - 1));
            const float x0f = floorf(xc), y0f = floorf(yc);
            rwx[k] = xc - x0f;  rwy[k] = yc - y0f;
            aR[k] = ((int)y0f - (Y - 4)) * WC + ((int)x0f - (XS - 4));
        }
    }

    float local = 0.f;

    for (int c = 0; c < Cn; ++c) {
        __syncthreads();                       // prior channel's reads done
        const float* __restrict__ Lc = Lb + (size_t)c * HW;
        const float* __restrict__ Rc = Rb + (size_t)c * HW;
        // ---- stage both windows: 1008 f4, fully coalesced ----
        #pragma unroll
        for (int k = 0; k < 4; ++k) {
            const int idx = k * BLK + tid;
            if (idx < 2 * F4P) {
                const int pl = idx >= F4P;
                const int f  = idx - pl * F4P;
                const int wr = f / F4W;
                const int c4 = f - wr * F4W;
                const int ys = min(max(Y - 4 + wr, 0), Hn - 1);
                const int xw = XS - 4 + c4 * 4;
                const float* __restrict__ src = (pl ? Rc : Lc) + (size_t)ys * Wn;
                f4 v;
                if (xw >= 0 && xw + 3 < Wn) {
                    v = *reinterpret_cast<const f4*>(src + xw);   // 16B-aligned
                } else {
                    v[0] = src[min(max(xw,     0), Wn - 1)];
                    v[1] = src[min(max(xw + 1, 0), Wn - 1)];
                    v[2] = src[min(max(xw + 2, 0), Wn - 1)];
                    v[3] = src[min(max(xw + 3, 0), Wn - 1)];
                }
                *reinterpret_cast<f4*>(&win[pl][wr][c4 * 4]) = v;
            }
        }
        __syncthreads();

        // ---- sample from LDS (divergent addressing is what LDS is for) ----
        const float* __restrict__ w0 = &win[0][0][0];
        const float* __restrict__ w1 = &win[1][0][0];
        #pragma unroll
        for (int k = 0; k < PXT; ++k) {
            const int i = k * BLK + tid;
            const int p = (Y + (i >> 6)) * Wn + XS + (i & 63);   // recomputed, no pgl[]
            const float g = Gb[(size_t)c * HW + p];
            const int a = aL[k];
            float v00 = w0[a],      v01 = w0[a + 1];
            float v10 = w0[a + WC], v11 = w0[a + WC + 1];
            float top = fmaf(lwx[k], v01 - v00, v00);
            float bot = fmaf(lwx[k], v11 - v10, v10);
            const float sL = fmaf(lwy[k], bot - top, top);
            const int a2 = aR[k];
            v00 = w1[a2];      v01 = w1[a2 + 1];
            v10 = w1[a2 + WC]; v11 = w1[a2 + WC + 1];
            top = fmaf(rwx[k], v01 - v00, v00);
            bot = fmaf(rwx[k], v11 - v10, v10);
            const float sR = fmaf(rwy[k], bot - top, top);
            local += fabsf(sL - g) + fabsf(sR - g);
        }
    }

    // wave(64) shuffle reduce -> LDS cross-wave -> one f64 atomic per block
    #pragma unroll
    for (int off = 32; off > 0; off >>= 1)
        local += __shfl_down(local, off, 64);

    __shared__ float wsum[4];
    const int lane = tid & 63;
    const int wid  = tid >> 6;
    if (lane == 0) wsum[wid] = local;
    __syncthreads();
    if (tid == 0) {
        const float s = wsum[0] + wsum[1] + wsum[2] + wsum[3];
        atomicAdd(accum, (double)s);
    }
}

__global__ void finalize_kernel(const double* __restrict__ accum,
                                float* __restrict__ out) {
    out[0] = (float)(accum[0] / (double)NTOT);
}

extern "C" void kernel_launch(void* const* d_in, const int* in_sizes, int n_in,
                              void* d_out, int out_size, void* d_ws, size_t ws_size,
                              hipStream_t stream) {
    const float* L   = (const float*)d_in[0];
    const float* R   = (const float*)d_in[1];
    const float* flm = (const float*)d_in[2];
    const float* frm = (const float*)d_in[3];
    const float* gt  = (const float*)d_in[4];
    double* accum = (double*)d_ws;

    (void)hipMemsetAsync(accum, 0, sizeof(double), stream);
    warp_loss_kernel<<<NWG, BLK, 0, stream>>>(L, R, flm, frm, gt, accum);
    finalize_kernel<<<1, 1, 0, stream>>>(accum, (float*)d_out);
}

// Round 15
// 123.779 us; speedup vs baseline: 2.2709x; 1.0691x over previous
//
#include <hip/hip_runtime.h>

constexpr int Bn = 8, Cn = 3, Hn = 720, Wn = 1280;
constexpr int HW = Hn * Wn;                    // 921600 px per image
constexpr long long NTOT = (long long)Bn * Cn * HW;

constexpr int BLK  = 256;
constexpr int TH   = 16, TW = 64;              // output tile 16x64 = 1024 px
constexpr int TPX  = TH * TW;
constexpr int TCOL = Wn / TW;                  // 20 tile-cols
constexpr int TPI  = (Hn / TH) * TCOL;         // 900 tiles per image
constexpr int NWG  = 8 * TPI;                  // 7200 blocks; bid&7 = image/XCD
constexpr int PXT  = TPX / BLK;                // 4 px per thread
constexpr int WR   = 24;                       // window rows: Y-4 .. Y+19 (border-replicated)
constexpr int WC   = 84;                       // window cols: XS-4 .. XS+79 (row = 336B = 21x16B, f4-aligned)
constexpr int F4W  = WC / 4;                   // 21 f4 per window row
constexpr int F4P  = WR * F4W;                 // 504 f4 per plane
constexpr int NF4  = 2 * F4P;                  // 1008 f4 per channel (both planes)

typedef float f4 __attribute__((ext_vector_type(4)));

// Gather one staged f4 for slot idx of channel plane pair (Lc, Rc).
__device__ __forceinline__ f4 stage_load(const float* __restrict__ Lc,
                                         const float* __restrict__ Rc,
                                         int idx, int Y, int XS) {
    const int pl = idx >= F4P;
    const int f  = idx - pl * F4P;
    const int wr = f / F4W;
    const int c4 = f - wr * F4W;
    const int ys = min(max(Y - 4 + wr, 0), Hn - 1);
    const int xw = XS - 4 + c4 * 4;
    const float* __restrict__ src = (pl ? Rc : Lc) + (size_t)ys * Wn;
    f4 v;
    if (xw >= 0 && xw + 3 < Wn) {
        v = *reinterpret_cast<const f4*>(src + xw);   // 16B-aligned fast path
    } else {
        v[0] = src[min(max(xw,     0), Wn - 1)];
        v[1] = src[min(max(xw + 1, 0), Wn - 1)];
        v[2] = src[min(max(xw + 2, 0), Wn - 1)];
        v[3] = src[min(max(xw + 3, 0), Wn - 1)];
    }
    return v;
}

__global__ __launch_bounds__(256) void warp_loss_kernel(
        const float* __restrict__ L, const float* __restrict__ R,
        const float* __restrict__ Flm, const float* __restrict__ Frm,
        const float* __restrict__ G, double* __restrict__ accum) {
    // XCD k (= bid%8) owns image k; t = tile id, row-major sweep (halo in L2).
    const int b    = blockIdx.x & 7;
    const int t    = blockIdx.x >> 3;          // [0, 900)
    const int trow = t / TCOL;
    const int tcol = t - trow * TCOL;
    const int Y    = trow * TH;
    const int XS   = tcol * TW;
    const int tid  = (int)threadIdx.x;

    const float* __restrict__ Lb = L + (size_t)b * Cn * HW;
    const float* __restrict__ Rb = R + (size_t)b * Cn * HW;
    const float* __restrict__ Gb = G + (size_t)b * Cn * HW;
    const float* __restrict__ fl = Flm + (size_t)b * 2 * HW;  // [0,HW)=x, [HW,2HW)=y
    const float* __restrict__ fr = Frm + (size_t)b * 2 * HW;

    __shared__ float win[2][2][WR][WC];        // 32.3 KB: [buf][plane][row][col]

    // ---- per-px tap state (channel-invariant), coalesced flow loads ----
    int   aL[PXT], aR[PXT];
    float lwx[PXT], lwy[PXT], rwx[PXT], rwy[PXT];
    #pragma unroll
    for (int k = 0; k < PXT; ++k) {
        const int i = k * BLK + tid;
        const int r = i >> 6, cm = i & 63;
        const int y = Y + r, x = XS + cm;
        const int p = y * Wn + x;
        {
            const float fx = fminf(fmaxf(fl[p],      -4.0f), 3.99951171875f);
            const float fy = fminf(fmaxf(fl[HW + p], -4.0f), 3.99951171875f);
            const float xc = fminf(fmaxf((float)x + fx, 0.f), (float)(Wn - 1));
            const float yc = fminf(fmaxf((float)y + fy, 0.f), (float)(Hn - 1));
            const float x0f = floorf(xc), y0f = floorf(yc);
            lwx[k] = xc - x0f;  lwy[k] = yc - y0f;
            aL[k] = ((int)y0f - (Y - 4)) * WC + ((int)x0f - (XS - 4));
        }
        {
            const float fx = fminf(fmaxf(fr[p],      -4.0f), 3.99951171875f);
            const float fy = fminf(fmaxf(fr[HW + p], -4.0f), 3.99951171875f);
            const float xc = fminf(fmaxf((float)x + fx, 0.f), (float)(Wn - 1));
            const float yc = fminf(fmaxf((float)y + fy, 0.f), (float)(Hn - 1));
            const float x0f = floorf(xc), y0f = floorf(yc);
            rwx[k] = xc - x0f;  rwy[k] = yc - y0f;
            aR[k] = ((int)y0f - (Y - 4)) * WC + ((int)x0f - (XS - 4));
        }
    }

    // ---- prologue: stage channel 0 into buffer 0 ----
    #pragma unroll
    for (int k = 0; k < 4; ++k) {
        const int idx = k * BLK + tid;
        if (idx < NF4) {
            const f4 v = stage_load(Lb, Rb, idx, Y, XS);
            const int pl = idx >= F4P;
            const int f  = idx - pl * F4P;
            const int wr = f / F4W;
            const int c4 = f - wr * F4W;
            *reinterpret_cast<f4*>(&win[0][pl][wr][c4 * 4]) = v;
        }
    }
    __syncthreads();

    float local = 0.f;

    for (int c = 0; c < Cn; ++c) {
        const int cur = c & 1;
        // ---- issue next channel's staging loads EARLY (T14 issue-early) ----
        f4 nx0, nx1, nx2, nx3;
        if (c < Cn - 1) {
            const float* __restrict__ Lc = Lb + (size_t)(c + 1) * HW;
            const float* __restrict__ Rc = Rb + (size_t)(c + 1) * HW;
            { const int idx = 0 * BLK + tid;                nx0 = stage_load(Lc, Rc, idx, Y, XS); }
            { const int idx = 1 * BLK + tid;                nx1 = stage_load(Lc, Rc, idx, Y, XS); }
            { const int idx = 2 * BLK + tid;                nx2 = stage_load(Lc, Rc, idx, Y, XS); }
            { const int idx = 3 * BLK + tid; if (idx < NF4) nx3 = stage_load(Lc, Rc, idx, Y, XS); }
        }

        // ---- sample channel c from win[cur] (latency of nx* hides here) ----
        const float* __restrict__ w0 = &win[cur][0][0][0];
        const float* __restrict__ w1 = &win[cur][1][0][0];
        #pragma unroll
        for (int k = 0; k < PXT; ++k) {
            const int i = k * BLK + tid;
            const int p = (Y + (i >> 6)) * Wn + XS + (i & 63);
            const float g = Gb[(size_t)c * HW + p];
            const int a = aL[k];
            float v00 = w0[a],      v01 = w0[a + 1];
            float v10 = w0[a + WC], v11 = w0[a + WC + 1];
            float top = fmaf(lwx[k], v01 - v00, v00);
            float bot = fmaf(lwx[k], v11 - v10, v10);
            const float sL = fmaf(lwy[k], bot - top, top);
            const int a2 = aR[k];
            v00 = w1[a2];      v01 = w1[a2 + 1];
            v10 = w1[a2 + WC]; v11 = w1[a2 + WC + 1];
            top = fmaf(rwx[k], v01 - v00, v00);
            bot = fmaf(rwx[k], v11 - v10, v10);
            const float sR = fmaf(rwy[k], bot - top, top);
            local += fabsf(sL - g) + fabsf(sR - g);
        }

        // ---- write next channel's window LATE into the other buffer ----
        if (c < Cn - 1) {
            float* __restrict__ wd = &win[cur ^ 1][0][0][0];
            #pragma unroll
            for (int k = 0; k < 4; ++k) {
                const int idx = k * BLK + tid;
                if (idx < NF4) {
                    const f4 v = (k == 0) ? nx0 : (k == 1) ? nx1 : (k == 2) ? nx2 : nx3;
                    const int pl = idx >= F4P;
                    const int f  = idx - pl * F4P;
                    const int wr = f / F4W;
                    const int c4 = f - wr * F4W;
                    *reinterpret_cast<f4*>(wd + ((size_t)pl * F4P * 4) + wr * WC + c4 * 4) = v;
                }
            }
            __syncthreads();
        }
    }

    // wave(64) shuffle reduce -> LDS cross-wave -> one f64 atomic per block
    #pragma unroll
    for (int off = 32; off > 0; off >>= 1)
        local += __shfl_down(local, off, 64);

    __shared__ float wsum[4];
    const int lane = tid & 63;
    const int wid  = tid >> 6;
    if (lane == 0) wsum[wid] = local;
    __syncthreads();
    if (tid == 0) {
        const float s = wsum[0] + wsum[1] + wsum[2] + wsum[3];
        atomicAdd(accum, (double)s);
    }
}

__global__ void finalize_kernel(const double* __restrict__ accum,
                                float* __restrict__ out) {
    out[0] = (float)(accum[0] / (double)NTOT);
}

extern "C" void kernel_launch(void* const* d_in, const int* in_sizes, int n_in,
                              void* d_out, int out_size, void* d_ws, size_t ws_size,
                              hipStream_t stream) {
    const float* L   = (const float*)d_in[0];
    const float* R   = (const float*)d_in[1];
    const float* flm = (const float*)d_in[2];
    const float* frm = (const float*)d_in[3];
    const float* gt  = (const float*)d_in[4];
    double* accum = (double*)d_ws;

    (void)hipMemsetAsync(accum, 0, sizeof(double), stream);
    warp_loss_kernel<<<NWG, BLK, 0, stream>>>(L, R, flm, frm, gt, accum);
    finalize_kernel<<<1, 1, 0, stream>>>(accum, (float*)d_out);
}